// Round 10
// baseline (92.990 us; speedup 1.0000x reference)
//
#include <hip/hip_runtime.h>
#include <hip/hip_bf16.h>
#include <math.h>

// SupConLoss, B=4096 V=2 D=128, N=8192.
// loss = (1/N) [ sum_i log(sum_{j!=i} exp(n_i.n_j/T)) - 2*sum_b spos_b ]
// Round 10: R9 fragment-major barrier-free main +
//  (a) wave-uniform BRANCH for the diagonal mask (predicated form cost ~15%
//      of hot-loop issue slots),
//  (b) fused two-level ticket finalize using agent-scope relaxed atomics +
//      explicit s_waitcnt vmcnt(0) — NO __threadfence (R3: fences = wbl2
//      flush = +50us). 2 dispatches total.

constexpr int   Bsz   = 4096;
constexpr int   Nrows = 8192;
constexpr int   Dd    = 128;
constexpr float TEMPf = 0.07f;
constexpr float EPSN  = 1e-8f;
constexpr float SCALE = 1.4426950408889634f / 0.07f;  // log2(e)/T
constexpr float LN2   = 0.6931471805599453f;

constexpr int CHUNKS     = 32;                 // col chunks (grid.x)
constexpr int CHUNK_COLS = Nrows / CHUNKS;     // 256
constexpr int CTS        = CHUNK_COLS / 32;    // 8 col-steps of 32
constexpr int ROWS_BLK   = 256;                // rows per block (4 waves x 64)
constexpr int YG         = Nrows / ROWS_BLK;   // 32 row-groups (grid.y)
constexpr int PREPBLKS   = Bsz / 4;            // 1024

typedef __attribute__((ext_vector_type(8)))  short bf16x8;   // 8 bf16 = 4 VGPRs
typedef __attribute__((ext_vector_type(16))) float floatx16; // MFMA 32x32 C/D

// Fragment-major n: row r = g*32+lo stores its 256 B as pieces
// addr = g*8192 + kc*1024 + hi*512 + lo*16  ->  wave fragment load (g,kc) is
// one fully-coalesced 1 KB global_load_dwordx4.

// ws layout (bytes):
//   0x000000  nF   fragment-major bf16 n   2 MB
//   0x200000  partial f32[32][8192]        1 MB
//   0x300000  sposPart f32[1024]           4 KB
//   0x301000  ylog f32[32]
//   0x301100  cnt  u32[33]  (per-y tickets + global)
constexpr size_t OFF_PART = 0x200000;
constexpr size_t OFF_SPOS = 0x300000;
constexpr size_t OFF_YLOG = 0x301000;
constexpr size_t OFF_CNT  = 0x301100;

// ------------- prep: normalize both views -> nF + spos sums + zero tickets -----
__global__ void prep_k(const float* __restrict__ f,
                       char* __restrict__ nF,
                       float* __restrict__ sposPart,
                       unsigned int* __restrict__ cnt) {
    __shared__ float sred[4];
    int tid  = threadIdx.x;
    int wid  = tid >> 6;
    int lane = tid & 63;
    int b    = blockIdx.x * 4 + wid;
    if (blockIdx.x == 0 && tid < 33) cnt[tid] = 0;   // tickets (ws is poisoned)

    const float* s0 = f + (size_t)(b * 2) * Dd;       // features[b, 0, :]
    float2 x = *(const float2*)(s0 + lane * 2);       // view 0
    float2 y = *(const float2*)(s0 + Dd + lane * 2);  // view 1
    float ss0 = x.x * x.x + x.y * x.y;
    float ss1 = y.x * y.x + y.y * y.y;
    float dt  = x.x * y.x + x.y * y.y;
    #pragma unroll
    for (int off = 32; off; off >>= 1) {
        ss0 += __shfl_xor(ss0, off);
        ss1 += __shfl_xor(ss1, off);
        dt  += __shfl_xor(dt,  off);
    }
    float inv0 = 1.0f / fmaxf(sqrtf(ss0), EPSN);
    float inv1 = 1.0f / fmaxf(sqrtf(ss1), EPSN);

    // lane holds k = 2*lane..2*lane+1 -> piece (kc=lane>>3, hi=(lane>>2)&1),
    // byte offset inside piece = (lane&3)*4
    int kc  = lane >> 3;
    int hi2 = (lane >> 2) & 1;
    size_t poff = (size_t)kc * 1024 + hi2 * 512 + (lane & 3) * 4;

    __hip_bfloat162 h;
    h.x = __float2bfloat16(x.x * inv0);
    h.y = __float2bfloat16(x.y * inv0);
    *(__hip_bfloat162*)(nF + (size_t)(b >> 5) * 8192 + (b & 31) * 16 + poff) = h;
    int r1 = Bsz + b;
    h.x = __float2bfloat16(y.x * inv1);
    h.y = __float2bfloat16(y.y * inv1);
    *(__hip_bfloat162*)(nF + (size_t)(r1 >> 5) * 8192 + (r1 & 31) * 16 + poff) = h;

    if (lane == 0) sred[wid] = dt * inv0 * inv1 / TEMPf;
    __syncthreads();
    if (tid == 0) sposPart[blockIdx.x] = sred[0] + sred[1] + sred[2] + sred[3];
}

// ------------- main: barrier-free GEMM + exp2 + row sums + ticket finalize -----
__global__ __launch_bounds__(256, 3)
void main_k(const char* __restrict__ nF, float* __restrict__ partial,
            const float* __restrict__ sposPart, float* __restrict__ ylog,
            unsigned int* __restrict__ cnt, float* __restrict__ out) {
    const int tid  = threadIdx.x;
    const int wid  = tid >> 6;
    const int lane = tid & 63;
    const int lo   = lane & 31;
    const int hi   = lane >> 5;
    const int gy   = blockIdx.y;
    const int rbase = gy * ROWS_BLK + wid * 64;          // wave's 64 rows
    const int cbase = blockIdx.x * CHUNK_COLS;           // 256-aligned

    // A fragments: two 32-row groups, 8 coalesced 1 KB loads each
    bf16x8 afrag[2][8];
    #pragma unroll
    for (int s = 0; s < 2; s++) {
        const char* ag = nF + (size_t)((rbase + s * 32) >> 5) * 8192 + lane * 16;
        #pragma unroll
        for (int kc = 0; kc < 8; kc++)
            afrag[s][kc] = *(const bf16x8*)(ag + kc * 1024);
    }

    float sums[2][16];
    #pragma unroll
    for (int s = 0; s < 2; s++)
        #pragma unroll
        for (int r = 0; r < 16; r++) sums[s][r] = 0.f;

    floatx16 zero = {};
    const char* bbase = nF + (size_t)(cbase >> 5) * 8192 + lane * 16;

    #pragma unroll 1
    for (int ct = 0; ct < CTS; ct++) {
        const char* bg = bbase + (size_t)ct * 8192;
        floatx16 acc0 = zero, acc1 = zero;
        #pragma unroll
        for (int kc = 0; kc < 8; kc++) {
            bf16x8 bf = *(const bf16x8*)(bg + kc * 1024);   // coalesced 1 KB
            acc0 = __builtin_amdgcn_mfma_f32_32x32x16_bf16(afrag[0][kc], bf, acc0, 0, 0, 0);
            acc1 = __builtin_amdgcn_mfma_f32_32x32x16_bf16(afrag[1][kc], bf, acc1, 0, 0, 0);
        }

        const int cb32 = cbase + ct * 32;
        #pragma unroll
        for (int s = 0; s < 2; s++) {
            const floatx16& acc = s ? acc1 : acc0;
            if (cb32 == rbase + s * 32) {     // wave-uniform, taken <=1 of 16
                #pragma unroll
                for (int r = 0; r < 16; r++) {
                    float e = __builtin_amdgcn_exp2f(acc[r] * SCALE);
                    // C/D: col=lo, row_local=(r&3)+8*(r>>2)+4*hi
                    if (lo == ((r & 3) + 8 * (r >> 2) + 4 * hi)) e = 0.f;
                    sums[s][r] += e;
                }
            } else {
                #pragma unroll
                for (int r = 0; r < 16; r++)
                    sums[s][r] += __builtin_amdgcn_exp2f(acc[r] * SCALE);
            }
        }
    }

    // row sums: reduce across 32 col-lanes; agent-coherent store of partials
    #pragma unroll
    for (int s = 0; s < 2; s++)
        #pragma unroll
        for (int r = 0; r < 16; r++) {
            float v = sums[s][r];
            #pragma unroll
            for (int off = 1; off < 32; off <<= 1) v += __shfl_xor(v, off);
            sums[s][r] = v;
        }
    if (lo == 0) {
        float* prow = partial + (size_t)blockIdx.x * Nrows;
        #pragma unroll
        for (int s = 0; s < 2; s++)
            #pragma unroll
            for (int r = 0; r < 16; r++) {
                int grow = rbase + s * 32 + (r & 3) + 8 * (r >> 2) + 4 * hi;
                __hip_atomic_store(&prow[grow], sums[s][r],
                                   __ATOMIC_RELAXED, __HIP_MEMORY_SCOPE_AGENT);
            }
    }

    // ---- two-level ticket finalize (atomics only; NO cache-flushing fences) ---
    __shared__ unsigned t1s, t2s;
    __shared__ float red[4];
    asm volatile("s_waitcnt vmcnt(0)" ::: "memory");   // partial stores done
    if (tid == 0) t1s = atomicAdd(&cnt[gy], 1u);
    __syncthreads();
    if (t1s == CHUNKS - 1) {                            // last x-block for gy
        int row = gy * ROWS_BLK + tid;
        float se = 0.f;
        #pragma unroll
        for (int c = 0; c < CHUNKS; c++)
            se += __hip_atomic_load(&partial[(size_t)c * Nrows + row],
                                    __ATOMIC_RELAXED, __HIP_MEMORY_SCOPE_AGENT);
        float lv = __builtin_amdgcn_logf(se) * LN2;     // v_log_f32 is log2
        #pragma unroll
        for (int off = 32; off; off >>= 1) lv += __shfl_xor(lv, off);
        if (lane == 0) red[wid] = lv;
        __syncthreads();
        if (tid == 0) {
            __hip_atomic_store(&ylog[gy], red[0] + red[1] + red[2] + red[3],
                               __ATOMIC_RELAXED, __HIP_MEMORY_SCOPE_AGENT);
            asm volatile("s_waitcnt vmcnt(0)" ::: "memory");
            t2s = atomicAdd(&cnt[32], 1u);
        }
        __syncthreads();
        if (t2s == YG - 1) {                            // very last y-group
            float a = 0.f;
            if (tid < YG)
                a = __hip_atomic_load(&ylog[tid],
                                      __ATOMIC_RELAXED, __HIP_MEMORY_SCOPE_AGENT);
            for (int i = tid; i < PREPBLKS; i += 256) a -= 2.f * sposPart[i];
            #pragma unroll
            for (int off = 32; off; off >>= 1) a += __shfl_xor(a, off);
            if (lane == 0) red[wid] = a;
            __syncthreads();
            if (tid == 0)
                out[0] = (red[0] + red[1] + red[2] + red[3]) / (float)Nrows;
        }
    }
}

extern "C" void kernel_launch(void* const* d_in, const int* in_sizes, int n_in,
                              void* d_out, int out_size, void* d_ws, size_t ws_size,
                              hipStream_t stream) {
    const float* f = (const float*)d_in[0];
    char* ws = (char*)d_ws;
    char* nF          = ws;
    float* partial    = (float*)(ws + OFF_PART);
    float* sposPart   = (float*)(ws + OFF_SPOS);
    float* ylog       = (float*)(ws + OFF_YLOG);
    unsigned int* cnt = (unsigned int*)(ws + OFF_CNT);

    prep_k<<<PREPBLKS, 256, 0, stream>>>(f, nF, sposPart, cnt);
    dim3 grid(CHUNKS, YG);
    main_k<<<grid, 256, 0, stream>>>(nF, partial, sposPart, ylog, cnt,
                                     (float*)d_out);
}

// Round 11
// 78.324 us; speedup vs baseline: 1.1873x; 1.1873x over previous
//
#include <hip/hip_runtime.h>
#include <hip/hip_bf16.h>
#include <math.h>

// SupConLoss, B=4096 V=2 D=128, N=8192.
// loss = (1/N) [ sum_i log(sum_{j!=i} exp(n_i.n_j/T)) - 2*sum_b spos_b ]
// Round 11: m97-pattern main kernel.
//  - B tiles staged via __builtin_amdgcn_global_load_lds width=16 (async DMA,
//    no VGPR round-trip) — the documented 1.7x ladder step never tried before.
//  - fragment-major nF: DMA lane order == fragment lane order (no swizzle).
//  - double-buffered 8 KB tiles, ONE barrier per tile.
//  - column-sum accumulation (row-sum == col-sum by symmetry): 1 scalar per
//    lane per tile instead of 32 accumulators + shuffle storm.
//  - 3 dispatches; NO tickets/fences (R3/R10: +7..50us).

constexpr int   Bsz   = 4096;
constexpr int   Nrows = 8192;
constexpr int   Dd    = 128;
constexpr float TEMPf = 0.07f;
constexpr float EPSN  = 1e-8f;
constexpr float SCALE = 1.4426950408889634f / 0.07f;  // log2(e)/T
constexpr float LN2   = 0.6931471805599453f;

constexpr int CHUNKS     = 32;                 // col chunks (grid.x)
constexpr int CHUNK_COLS = Nrows / CHUNKS;     // 256
constexpr int TILES      = CHUNK_COLS / 32;    // 8 tiles of 32 cols
constexpr int ROWS_BLK   = 256;                // rows per block (4 waves x 64)
constexpr int YG         = Nrows / ROWS_BLK;   // 32 (grid.y)
constexpr int PREPBLKS   = Bsz / 4;            // 1024

typedef __attribute__((ext_vector_type(8)))  short bf16x8;   // 8 bf16 = 4 VGPRs
typedef __attribute__((ext_vector_type(16))) float floatx16; // MFMA 32x32 C/D

// Fragment-major n: row r = g*32+lo stores its 256 B as pieces at
// g*8192 + kc*1024 + hi*512 + lo*16. Wave fragment load (g,kc) =
// base + g*8192 + kc*1024 + lane*16 — one coalesced 1 KB access, and the
// global_load_lds hardware placement (lds_base + lane*16) reproduces it in LDS.

// ws layout (bytes):
//   0x000000  nF   fragment-major bf16 n   2 MB
//   0x200000  partial f32[32][8192]        1 MB   (col sums per row-group)
//   0x300000  sposPart f32[1024]           4 KB
constexpr size_t OFF_PART = 0x200000;
constexpr size_t OFF_SPOS = 0x300000;

__device__ __forceinline__ void gld_lds16(const void* g, void* l) {
    __builtin_amdgcn_global_load_lds(
        (const __attribute__((address_space(1))) void*)g,
        (__attribute__((address_space(3))) void*)l, 16, 0, 0);
}

// ------------- prep: normalize both views -> nF + per-block spos sums ----------
__global__ void prep_k(const float* __restrict__ f,
                       char* __restrict__ nF,
                       float* __restrict__ sposPart,
                       float* __restrict__ out) {
    __shared__ float sred[4];
    int tid  = threadIdx.x;
    int wid  = tid >> 6;
    int lane = tid & 63;
    int b    = blockIdx.x * 4 + wid;
    if (blockIdx.x == 0 && tid == 0) out[0] = 0.f;   // final_k accumulates

    const float* s0 = f + (size_t)(b * 2) * Dd;       // features[b, 0, :]
    float2 x = *(const float2*)(s0 + lane * 2);       // view 0
    float2 y = *(const float2*)(s0 + Dd + lane * 2);  // view 1
    float ss0 = x.x * x.x + x.y * x.y;
    float ss1 = y.x * y.x + y.y * y.y;
    float dt  = x.x * y.x + x.y * y.y;
    #pragma unroll
    for (int off = 32; off; off >>= 1) {
        ss0 += __shfl_xor(ss0, off);
        ss1 += __shfl_xor(ss1, off);
        dt  += __shfl_xor(dt,  off);
    }
    float inv0 = 1.0f / fmaxf(sqrtf(ss0), EPSN);
    float inv1 = 1.0f / fmaxf(sqrtf(ss1), EPSN);

    // lane holds k = 2*lane..2*lane+1 -> piece (kc=lane>>3, hi=(lane>>2)&1),
    // byte offset inside piece = (lane&3)*4
    size_t poff = (size_t)(lane >> 3) * 1024 + ((lane >> 2) & 1) * 512
                + (lane & 3) * 4;

    __hip_bfloat162 h;
    h.x = __float2bfloat16(x.x * inv0);
    h.y = __float2bfloat16(x.y * inv0);
    *(__hip_bfloat162*)(nF + (size_t)(b >> 5) * 8192 + (b & 31) * 16 + poff) = h;
    int r1 = Bsz + b;
    h.x = __float2bfloat16(y.x * inv1);
    h.y = __float2bfloat16(y.y * inv1);
    *(__hip_bfloat162*)(nF + (size_t)(r1 >> 5) * 8192 + (r1 & 31) * 16 + poff) = h;

    if (lane == 0) sred[wid] = dt * inv0 * inv1 / TEMPf;
    __syncthreads();
    if (tid == 0) sposPart[blockIdx.x] = sred[0] + sred[1] + sred[2] + sred[3];
}

// ------------- main: async-LDS GEMM + exp2 + column sums -----------------------
// Grid (32 chunks, 32 row-groups), 256 thr = 4 waves. Wave: 64 rows x 32-col
// tiles. B tile (8 KB) double-buffered via global_load_lds (2 instrs/wave),
// one barrier per tile. Column sums (== row sums by symmetry): one scalar per
// lane per tile -> LDS strip -> coalesced partial[gy][cbase..+255] store.
__global__ __launch_bounds__(256, 3)
void main_k(const char* __restrict__ nF, float* __restrict__ partial) {
    __shared__ char  bufs[2][8192];
    __shared__ float colred[4][256];
    const int tid  = threadIdx.x;
    const int wid  = tid >> 6;
    const int lane = tid & 63;
    const int lo   = lane & 31;
    const int hi   = lane >> 5;
    const int gy   = blockIdx.y;
    const int rbase = gy * ROWS_BLK + wid * 64;          // wave's 64 rows
    const int cbase = blockIdx.x * CHUNK_COLS;           // 256-aligned
    const int cg0   = cbase >> 5;                        // first col group

    // A fragments: two 32-row groups, 8 coalesced 1 KB loads each (64 VGPRs)
    bf16x8 afrag[2][8];
    #pragma unroll
    for (int s = 0; s < 2; s++) {
        const char* ag = nF + (size_t)((rbase + s * 32) >> 5) * 8192 + lane * 16;
        #pragma unroll
        for (int kc = 0; kc < 8; kc++)
            afrag[s][kc] = *(const bf16x8*)(ag + kc * 1024);
    }

    // stage tile 0 (each wave DMAs fragments kc = 2*wid, 2*wid+1)
    {
        const char* g0 = nF + (size_t)cg0 * 8192;
        int kc = wid * 2;
        gld_lds16(g0 + kc * 1024 + lane * 16,       &bufs[0][kc * 1024]);
        gld_lds16(g0 + (kc + 1) * 1024 + lane * 16, &bufs[0][(kc + 1) * 1024]);
    }

    floatx16 zero = {};

    #pragma unroll 1
    for (int t = 0; t < TILES; t++) {
        // barrier: (a) tile t's DMA drained (compiler emits vmcnt(0) before
        // s_barrier), (b) all waves done reading the buffer we stage into next
        __syncthreads();
        if (t + 1 < TILES) {
            const char* gn = nF + (size_t)(cg0 + t + 1) * 8192;
            char* dst = bufs[(t + 1) & 1];
            int kc = wid * 2;
            gld_lds16(gn + kc * 1024 + lane * 16,       dst + kc * 1024);
            gld_lds16(gn + (kc + 1) * 1024 + lane * 16, dst + (kc + 1) * 1024);
        }

        const char* buf = bufs[t & 1];
        floatx16 acc0 = zero, acc1 = zero;
        #pragma unroll
        for (int kc = 0; kc < 8; kc++) {
            bf16x8 bf = *(const bf16x8*)&buf[kc * 1024 + lane * 16];
            acc0 = __builtin_amdgcn_mfma_f32_32x32x16_bf16(afrag[0][kc], bf, acc0, 0, 0, 0);
            acc1 = __builtin_amdgcn_mfma_f32_32x32x16_bf16(afrag[1][kc], bf, acc1, 0, 0, 0);
        }

        // epilogue: exp2, diagonal mask (wave-uniform branch), COLUMN sums
        const int cb32 = cbase + t * 32;
        float cs = 0.f;
        #pragma unroll
        for (int s = 0; s < 2; s++) {
            const floatx16& acc = s ? acc1 : acc0;
            if (cb32 == rbase + s * 32) {     // taken <=1 of 16 (s,t) combos
                #pragma unroll
                for (int r = 0; r < 16; r++) {
                    float e = __builtin_amdgcn_exp2f(acc[r] * SCALE);
                    // C/D layout: col=lo, row_local=(r&3)+8*(r>>2)+4*hi
                    if (lo == ((r & 3) + 8 * (r >> 2) + 4 * hi)) e = 0.f;
                    cs += e;
                }
            } else {
                #pragma unroll
                for (int r = 0; r < 16; r++)
                    cs += __builtin_amdgcn_exp2f(acc[r] * SCALE);
            }
        }
        cs += __shfl_xor(cs, 32);             // fold the two row-half lanes
        if (hi == 0) colred[wid][t * 32 + lo] = cs;
    }

    __syncthreads();
    // cross-wave: block's col sums over its 256-row stripe, coalesced store
    float v = colred[0][tid] + colred[1][tid] + colred[2][tid] + colred[3][tid];
    partial[(size_t)gy * Nrows + cbase + tid] = v;
}

// ------------- finalize: 32 blocks; atomicAdd the scalar -----------------------
// se[r] = sum_gy partial[gy][r]  (column sum == row sum of exp matrix)
__global__ __launch_bounds__(256)
void final_k(const float* __restrict__ partial, const float* __restrict__ sposPart,
             float* __restrict__ out) {
    __shared__ float red[4];
    int tid = threadIdx.x;
    int r = blockIdx.x * 256 + tid;
    float se = 0.f;
    #pragma unroll
    for (int p = 0; p < YG; p++) se += partial[(size_t)p * Nrows + r];
    float acc = __builtin_amdgcn_logf(se) * LN2;   // v_log_f32 is log2
    if (tid < 32) acc -= 2.f * sposPart[blockIdx.x * 32 + tid];
    #pragma unroll
    for (int off = 32; off; off >>= 1) acc += __shfl_xor(acc, off);
    if ((tid & 63) == 0) red[tid >> 6] = acc;
    __syncthreads();
    if (tid == 0)
        atomicAdd(out, (red[0] + red[1] + red[2] + red[3]) / (float)Nrows);
}

extern "C" void kernel_launch(void* const* d_in, const int* in_sizes, int n_in,
                              void* d_out, int out_size, void* d_ws, size_t ws_size,
                              hipStream_t stream) {
    const float* f = (const float*)d_in[0];
    char* ws = (char*)d_ws;
    char* nF        = ws;
    float* partial  = (float*)(ws + OFF_PART);
    float* sposPart = (float*)(ws + OFF_SPOS);

    prep_k<<<PREPBLKS, 256, 0, stream>>>(f, nF, sposPart, (float*)d_out);
    dim3 grid(CHUNKS, YG);
    main_k<<<grid, 256, 0, stream>>>(nF, partial);
    final_k<<<Nrows / 256, 256, 0, stream>>>(partial, sposPart, (float*)d_out);
}